// Round 17
// baseline (121.668 us; speedup 1.0000x reference)
//
#include <hip/hip_runtime.h>
#include <hip/hip_bf16.h>

#define STATE 16
#define DNA_C 4
#define HID   128
#define FAN1  52
#define HH    256
#define WW    256
#define HW    (HH * WW)

typedef unsigned short u16;
typedef unsigned int   u32;
typedef short bf8 __attribute__((ext_vector_type(8)));
typedef float f32x4 __attribute__((ext_vector_type(4)));

__device__ __forceinline__ u32 pk(float a, float b) {
    __hip_bfloat162 t = __float22bfloat162_rn(make_float2(a, b));  // v_cvt_pk_bf16_f32
    union { __hip_bfloat162 h; u32 u; } c; c.h = t; return c.u;
}
__device__ __forceinline__ u16 f2bf(float f) {
    union { __hip_bfloat16 h; u16 u; } c; c.h = __float2bfloat16(f); return c.u;
}

// w1 [128][52] f32 -> bf16 [128][64], DOUBLY permuted (identical to round 13):
//  * k-permutation: knew = 16w + t (t0-3 x, t4-7 gx, t8-11 gy, t12-15 dna(w==0)/pad)
//  * M-permutation: physical row p=16m+4g+r holds true hidden H = 32(m>>1)+8g+4(m&1)+r
//    -> L1 D-fragment IS the L2 B-fragment (register-only layer-2 exchange).
// w2 [16][128] -> bf16 plain.
__global__ void prep_weights(const float* __restrict__ w1, const float* __restrict__ w2,
                             u16* __restrict__ wb) {
    int i = blockIdx.x * 256 + threadIdx.x;   // 0..10239
    if (i < 128 * 64) {
        int p = i >> 6, knew = i & 63;
        int m = p >> 4, g = (p >> 2) & 3, r = p & 3;
        int hrow = 32 * (m >> 1) + 8 * g + 4 * (m & 1) + r;   // true hidden row at physical p
        int w = knew >> 4, t = knew & 15;
        float v = 0.f;
        if (t < 4)        v = w1[hrow * FAN1 + 4 * w + t];
        else if (t < 8)   v = w1[hrow * FAN1 + 16 + 4 * w + (t - 4)];
        else if (t < 12)  v = w1[hrow * FAN1 + 32 + 4 * w + (t - 8)];
        else if (w == 0)  v = w1[hrow * FAN1 + 48 + (t - 12)];
        wb[i] = f2bf(v);
    } else if (i < 128 * 64 + 16 * 128) {
        wb[i] = f2bf(w2[i - 128 * 64]);
    }
}

__global__ __launch_bounds__(256, 3) void update_net17(
    const float* __restrict__ x,    // [B,16,256,256]
    const float* __restrict__ dna,  // [B,4,256,256]
    const u16*   __restrict__ wb,   // permuted bf16 w1 [128][64], w2 [16][128]
    float* __restrict__ out,        // [B,16,256,256]
    int nrows)                      // B*256
{
    // Round-16 persistent chunked structure + ROW-CARRY:
    //  * carried per wave: A = x[y-1], B = x[y] (32 VGPRs, its 4 channels, 4 px/lane);
    //    only C = x[y+1] is loaded per iteration (4 f32x4 vs 12) -> x fetched once/row.
    //  * rotate+load for the NEXT row issued after the first barrier, BEFORE the MFMA
    //    loop: HBM latency hides under MFMA+pack; the 2nd barrier's vmcnt drain lands
    //    after the latency elapsed.
    //  * image borders are data-zeroed (A=0 at y==0, C=0 at y==255) -> no ht/hb branches.
    __shared__ __align__(16) u16 feat_lds[256 * 64];

    const int tid  = threadIdx.x;
    const int lane = tid & 63;
    const int wv   = tid >> 6;
    const int fj   = lane & 15;   // A-row / B-col / D-col
    const int fg   = lane >> 4;   // k-group (A/B), row-group (D)
    const int f4   = fj >> 2;     // feat read swizzle base
    const int px0  = lane * 4;

    // ---- weight fragments ONCE per block (register-resident, r13 layout) ----
    const u16* w1b = wb;             // [128][64] doubly permuted
    const u16* w2b = wb + 128 * 64;  // [16][128]
    bf8 a1[8][2];
    #pragma unroll
    for (int m = 0; m < 8; ++m) {
        #pragma unroll
        for (int kt = 0; kt < 2; ++kt)
            a1[m][kt] = *(const bf8*)&w1b[(16 * m + fj) * 64 + 32 * kt + 8 * fg];
    }
    bf8 a2[4];
    #pragma unroll
    for (int kt = 0; kt < 4; ++kt)
        a2[kt] = *(const bf8*)&w2b[fj * 128 + 32 * kt + 8 * fg];

    // ---- bijective contiguous chunking of rows over blocks ----
    const int ngrid = gridDim.x;
    const int q = nrows / ngrid, rm = nrows - q * ngrid;
    const int bid = blockIdx.x;
    const int start = (bid < rm) ? bid * (q + 1) : rm * (q + 1) + (bid - rm) * q;
    const int cnt   = (bid < rm) ? q + 1 : q;

    // ---- carried stencil rows (per wave: its 4 channels, 4 px/lane) ----
    f32x4 A[4], B[4], C[4];
#define LOADX(dst, bb, yy)                                                              \
    do {                                                                                \
        const float* _p = x + (((size_t)((bb) * STATE + 4 * wv)) * HH + (yy)) * WW + px0; \
        dst[0] = *(const f32x4*)_p;                                                     \
        dst[1] = *(const f32x4*)(_p + HW);                                              \
        dst[2] = *(const f32x4*)(_p + 2 * HW);                                          \
        dst[3] = *(const f32x4*)(_p + 3 * HW);                                          \
    } while (0)
#define ZEROX(dst)                                                                      \
    do { _Pragma("unroll") for (int _c = 0; _c < 4; ++_c)                               \
         { dst[_c][0] = 0.f; dst[_c][1] = 0.f; dst[_c][2] = 0.f; dst[_c][3] = 0.f; } } while (0)

    {   // prologue for first row of the chunk
        const int b0 = start >> 8, y0 = start & 255;
        if (y0 > 0) LOADX(A, b0, y0 - 1); else ZEROX(A);
        LOADX(B, b0, y0);
        if (y0 < HH - 1) LOADX(C, b0, y0 + 1); else ZEROX(C);
    }

    for (int it = 0; it < cnt; ++it) {
        const int yr = start + it;
        const int b  = yr >> 8;
        const int y  = yr & 255;

        // ---- feature phase: Sobel from carried A(t), B(m), C(b); no border branches ----
        {
            f32x4 gx[4], gy[4];
            #pragma unroll
            for (int c = 0; c < 4; ++c) {
                f32x4 cs, d;
                #pragma unroll
                for (int i = 0; i < 4; ++i) {
                    cs[i] = fmaf(2.f, B[c][i], A[c][i] + C[c][i]);   // colsum t+2m+b
                    d[i]  = C[c][i] - A[c][i];
                }
                float csL = __shfl_up(cs[3], 1);
                float csR = __shfl_down(cs[0], 1);
                float dL  = __shfl_up(d[3], 1);
                float dR  = __shfl_down(d[0], 1);
                if (lane == 0)  { csL = 0.f; dL = 0.f; }       // image left border
                if (lane == 63) { csR = 0.f; dR = 0.f; }       // image right border
                gx[c][0] = cs[1] - csL;   gx[c][1] = cs[2] - cs[0];
                gx[c][2] = cs[3] - cs[1]; gx[c][3] = csR - cs[2];
                gy[c][0] = fmaf(2.f, d[0], dL + d[1]);
                gy[c][1] = fmaf(2.f, d[1], d[0] + d[2]);
                gy[c][2] = fmaf(2.f, d[2], d[1] + d[3]);
                gy[c][3] = fmaf(2.f, d[3], d[2] + dR);
            }
            f32x4 dn[4] = {{0,0,0,0},{0,0,0,0},{0,0,0,0},{0,0,0,0}};
            if (wv == 0) {
                #pragma unroll
                for (int dc = 0; dc < 4; ++dc)
                    dn[dc] = *(const f32x4*)(dna + (((size_t)(b * DNA_C + dc)) * HH + y) * WW + px0);
            }
            const int s = lane & 7;   // (px>>2)&7 for all 4 px of this lane
            #pragma unroll
            for (int i = 0; i < 4; ++i) {
                u16* rowp = &feat_lds[(px0 + i) * 64];
                uint4 c0 = make_uint4(pk(B[0][i],  B[1][i]),  pk(B[2][i],  B[3][i]),
                                      pk(gx[0][i], gx[1][i]), pk(gx[2][i], gx[3][i]));
                uint4 c1 = make_uint4(pk(gy[0][i], gy[1][i]), pk(gy[2][i], gy[3][i]),
                                      pk(dn[0][i], dn[1][i]), pk(dn[2][i], dn[3][i]));
                *(uint4*)&rowp[8 * ((2 * wv)     ^ s)] = c0;   // knew 16wv..+7  : x | gx
                *(uint4*)&rowp[8 * ((2 * wv + 1) ^ s)] = c1;   // knew 16wv+8..15: gy | dna/pad
            }
        }

        __syncthreads();   // feature phase is cross-wave

        // ---- rotate + prefetch NEXT row's stencil (latency hides under MFMA below) ----
        if (it + 1 < cnt) {
            const int nyr = yr + 1;
            const int ny  = nyr & 255;
            if (ny == 0) {              // batch boundary: full reload
                const int nb = nyr >> 8;
                ZEROX(A);
                LOADX(B, nb, 0);
                LOADX(C, nb, 1);
            } else {
                #pragma unroll
                for (int c = 0; c < 4; ++c) { A[c] = B[c]; B[c] = C[c]; }
                if (ny < HH - 1) LOADX(C, yr >> 8, ny + 1); else ZEROX(C);
            }
        }

        // ---- MLP per g4 (unchanged r13 body) ----
        #pragma unroll
        for (int g4 = 0; g4 < 4; ++g4) {
            const int r  = wv * 64 + g4 * 16 + fj;
            const int sg = (4 * g4 + f4) & 7;
            bf8 b0 = *(const bf8*)&feat_lds[r * 64 + 8 * ((0 + fg) ^ sg)];
            bf8 b1 = *(const bf8*)&feat_lds[r * 64 + 8 * ((4 + fg) ^ sg)];

            u32 w[8][2];
            #pragma unroll
            for (int mh = 0; mh < 2; ++mh) {
                f32x4 hc[4];
                #pragma unroll
                for (int mm = 0; mm < 4; ++mm) {
                    const int m = mh * 4 + mm;
                    f32x4 z = {0.f, 0.f, 0.f, 0.f};
                    z = __builtin_amdgcn_mfma_f32_16x16x32_bf16(a1[m][0], b0, z, 0, 0, 0);
                    hc[mm] = __builtin_amdgcn_mfma_f32_16x16x32_bf16(a1[m][1], b1, z, 0, 0, 0);
                }
                #pragma unroll
                for (int mm = 0; mm < 4; ++mm) {
                    const int m = mh * 4 + mm;
                    w[m][0] = pk(fmaxf(hc[mm][0], 0.f), fmaxf(hc[mm][1], 0.f));
                    w[m][1] = pk(fmaxf(hc[mm][2], 0.f), fmaxf(hc[mm][3], 0.f));
                }
            }

            f32x4 uacc = {0.f, 0.f, 0.f, 0.f};
            #pragma unroll
            for (int kt = 0; kt < 4; ++kt) {
                union { u32 u[4]; bf8 v; } bbu;
                bbu.u[0] = w[2 * kt][0];
                bbu.u[1] = w[2 * kt][1];
                bbu.u[2] = w[2 * kt + 1][0];
                bbu.u[3] = w[2 * kt + 1][1];
                uacc = __builtin_amdgcn_mfma_f32_16x16x32_bf16(a2[kt], bbu.v, uacc, 0, 0, 0);
            }

            const int xo = wv * 64 + g4 * 16 + fj;
            float* po = out + (((size_t)(b * STATE + 4 * fg)) * HH + y) * WW + xo;
            #pragma unroll
            for (int rr2 = 0; rr2 < 4; ++rr2)
                po[(size_t)rr2 * HW] = uacc[rr2];
        }

        __syncthreads();   // this row's MFMA reads done before next row's feat writes
    }
#undef LOADX
#undef ZEROX
}

extern "C" void kernel_launch(void* const* d_in, const int* in_sizes, int n_in,
                              void* d_out, int out_size, void* d_ws, size_t ws_size,
                              hipStream_t stream) {
    const float* x   = (const float*)d_in[0];
    const float* dna = (const float*)d_in[1];
    const float* w1  = (const float*)d_in[2];
    const float* w2  = (const float*)d_in[3];
    float* out = (float*)d_out;
    u16* wb = (u16*)d_ws;   // 10240 u16 = 20 KB

    prep_weights<<<dim3(40), dim3(256), 0, stream>>>(w1, w2, wb);

    const int B = in_sizes[0] / (STATE * HH * WW);   // 16
    const int nrows = B * HH;                        // 4096
    const int grid = (nrows < 768) ? nrows : 768;    // 3 blocks/CU persistent
    update_net17<<<dim3(grid), dim3(256), 0, stream>>>(x, dna, wb, out, nrows);
}

// Round 18
// 78.862 us; speedup vs baseline: 1.5428x; 1.5428x over previous
//
#include <hip/hip_runtime.h>
#include <hip/hip_bf16.h>

#define STATE 16
#define DNA_C 4
#define HID   128
#define FAN1  52
#define HH    256
#define WW    256
#define HW    (HH * WW)

typedef unsigned short u16;
typedef unsigned int   u32;
typedef short bf8 __attribute__((ext_vector_type(8)));
typedef float f32x4 __attribute__((ext_vector_type(4)));

// two-level LDS chunk swizzle: bijective in c for fixed px; spreads rows AND chunks
#define SWZ(c, p) (((((c) + ((p) >> 3)) & 7)) ^ ((p) & 7))

__device__ __forceinline__ u32 pk(float a, float b) {
    __hip_bfloat162 t = __float22bfloat162_rn(make_float2(a, b));  // v_cvt_pk_bf16_f32
    union { __hip_bfloat162 h; u32 u; } c; c.h = t; return c.u;
}
__device__ __forceinline__ u16 f2bf(float f) {
    union { __hip_bfloat16 h; u16 u; } c; c.h = __float2bfloat16(f); return c.u;
}

// w1 [128][52] f32 -> bf16 [128][64], doubly permuted (identical to round 14):
//  * k-layout: knew = 16*c4 + 4*t2 + e -> true feat = 16*t2 + (c4+4e) for t2<3 (x/gx/gy),
//    t2==3: e==0 -> dna (48+c4), else zero-pad.  (matches the wave-private feature layout)
//  * M-permutation (hidden reorder, r13): physical row p=16m+4g+r holds true hidden
//    H = 32*(m>>1) + 8g + 4*(m&1) + r  ->  L1 D-frag IS the L2 B-frag (register-only L2).
// w2 [16][128] -> bf16 plain.
__global__ void prep_weights(const float* __restrict__ w1, const float* __restrict__ w2,
                             u16* __restrict__ wb) {
    int i = blockIdx.x * 256 + threadIdx.x;   // 0..10239
    if (i < 128 * 64) {
        int p = i >> 6, knew = i & 63;
        int m = p >> 4, g = (p >> 2) & 3, r = p & 3;
        int hrow = 32 * (m >> 1) + 8 * g + 4 * (m & 1) + r;
        int c4 = knew >> 4, t2 = (knew >> 2) & 3, e = knew & 3;
        float v = 0.f;
        if (t2 < 3)       v = w1[hrow * FAN1 + 16 * t2 + c4 + 4 * e];
        else if (e == 0)  v = w1[hrow * FAN1 + 48 + c4];
        wb[i] = f2bf(v);
    } else if (i < 128 * 64 + 16 * 128) {
        wb[i] = f2bf(w2[i - 128 * 64]);
    }
}

__global__ __launch_bounds__(256, 3) void update_net18(
    const float* __restrict__ x,    // [B,16,256,256]
    const float* __restrict__ dna,  // [B,4,256,256]
    const u16*   __restrict__ wb,   // permuted bf16 w1 [128][64], w2 [16][128]
    float* __restrict__ out,        // [B,16,256,256]
    int nrows)                      // B*256
{
    // Round-14 barrier-free wave-private body + round-16 contiguous chunking:
    //  * wave wv owns px segment [64wv, 64wv+64) for ALL 16 channels; its LDS region
    //    is private -> ZERO __syncthreads in the kernel; waves free-run, so next-row
    //    loads overlap this-row MFMA without carried registers (in-order per-wave DS).
    //  * block i owns a CONTIGUOUS row chunk -> row y+1 re-reads rows y,y+1 from L1/L2;
    //    weight fragments loaded once per block.
    __shared__ __align__(16) u16 feat_lds[4][64 * 64];

    const int tid  = threadIdx.x;
    const int lane = tid & 63;
    const int wv   = tid >> 6;
    const int c4   = lane >> 4;     // channel sub-index (feature) == fg (MLP)
    const int p16  = lane & 15;     // px-group (feature)          == fj (MLP)
    const int fj   = p16, fg = c4;
    const int px0  = wv * 64;       // wave's global px base

    // ---- weight fragments once per block (register-resident, r13 layout) ----
    const u16* w1b = wb;             // [128][64] doubly permuted
    const u16* w2b = wb + 128 * 64;  // [16][128]
    bf8 a1[8][2];
    #pragma unroll
    for (int m = 0; m < 8; ++m) {
        #pragma unroll
        for (int kt = 0; kt < 2; ++kt)
            a1[m][kt] = *(const bf8*)&w1b[(16 * m + fj) * 64 + 32 * kt + 8 * fg];
    }
    bf8 a2[4];
    #pragma unroll
    for (int kt = 0; kt < 4; ++kt)
        a2[kt] = *(const bf8*)&w2b[fj * 128 + 32 * kt + 8 * fg];

    u16* fw = &feat_lds[wv][0];

    // segment-edge halo: lane p16==0 needs px0-1, lane p16==15 needs px0+64
    const int  eoff = (p16 == 0) ? -1 : 4;     // offset from lane's own base pointer
    const bool pe   = (p16 == 0) ? (wv > 0) : ((p16 == 15) ? (wv < 3) : false);

    // ---- bijective contiguous chunking of rows over blocks ----
    const int ngrid = gridDim.x;
    const int q = nrows / ngrid, rm = nrows - q * ngrid;
    const int bid = blockIdx.x;
    const int start = (bid < rm) ? bid * (q + 1) : rm * (q + 1) + (bid - rm) * q;
    const int cnt   = (bid < rm) ? q + 1 : q;

    for (int it = 0; it < cnt; ++it) {
        const int yr = start + it;
        const int b = yr >> 8;
        const int y = yr & 255;
        const bool ht = (y > 0), hb = (y < HH - 1);
        const int pxl = px0 + 4 * p16;

        // ---- feature rounds: t=0..3, lane handles channel c4+4t, 4 px ----
        f32x4 sx[4], sgx[4], sgy[4];
        #pragma unroll
        for (int t = 0; t < 4; ++t) {
            const float* p = x + (((size_t)(b * STATE + c4 + 4 * t)) * HH + y) * WW + pxl;
            f32x4 m4 = *(const f32x4*)p;
            f32x4 t4 = {0.f,0.f,0.f,0.f}, b4 = {0.f,0.f,0.f,0.f};
            if (ht) t4 = *(const f32x4*)(p - WW);
            if (hb) b4 = *(const f32x4*)(p + WW);
            float mE = 0.f, tE = 0.f, bE = 0.f;
            if (pe) {
                mE = p[eoff];
                if (ht) tE = p[eoff - WW];
                if (hb) bE = p[eoff + WW];
            }
            f32x4 cs, d;
            #pragma unroll
            for (int i = 0; i < 4; ++i) {
                cs[i] = fmaf(2.f, m4[i], t4[i] + b4[i]);   // colsum t+2m+b
                d[i]  = b4[i] - t4[i];
            }
            const float csE = fmaf(2.f, mE, tE + bE);
            const float dE  = bE - tE;
            float csL = __shfl_up(cs[3], 1);
            float csR = __shfl_down(cs[0], 1);
            float dL  = __shfl_up(d[3], 1);
            float dR  = __shfl_down(d[0], 1);
            if (p16 == 0)  { csL = csE; dL = dE; }   // segment/image left edge
            if (p16 == 15) { csR = csE; dR = dE; }   // segment/image right edge
            sx[t] = m4;
            sgx[t][0] = cs[1] - csL;   sgx[t][1] = cs[2] - cs[0];
            sgx[t][2] = cs[3] - cs[1]; sgx[t][3] = csR - cs[2];
            sgy[t][0] = fmaf(2.f, d[0], dL + d[1]);
            sgy[t][1] = fmaf(2.f, d[1], d[0] + d[2]);
            sgy[t][2] = fmaf(2.f, d[2], d[1] + d[3]);
            sgy[t][3] = fmaf(2.f, d[3], d[2] + dR);
        }
        const f32x4 dn = *(const f32x4*)(dna + (((size_t)(b * DNA_C + c4)) * HH + y) * WW + pxl);

        // ---- LDS writes: lane owns k [16c4, 16c4+16) of its 4 px -> 2 b128 per px ----
        #pragma unroll
        for (int i = 0; i < 4; ++i) {
            const int px = 4 * p16 + i;   // local row
            uint4 q0 = make_uint4(pk(sx[0][i],  sx[1][i]),  pk(sx[2][i],  sx[3][i]),
                                  pk(sgx[0][i], sgx[1][i]), pk(sgx[2][i], sgx[3][i]));
            uint4 q1 = make_uint4(pk(sgy[0][i], sgy[1][i]), pk(sgy[2][i], sgy[3][i]),
                                  pk(dn[i], 0.f), 0u);
            *(uint4*)&fw[px * 64 + 8 * SWZ(2 * c4,     px)] = q0;   // k 16c4..+7 : x|gx
            *(uint4*)&fw[px * 64 + 8 * SWZ(2 * c4 + 1, px)] = q1;   // k +8..+15 : gy|dna
        }

        // ---- MLP per g4 (wave-private reads; in-order DS orders vs next-row writes) ----
        #pragma unroll
        for (int g4 = 0; g4 < 4; ++g4) {
            const int r = g4 * 16 + fj;   // local row
            bf8 b0 = *(const bf8*)&fw[r * 64 + 8 * SWZ(fg,     r)];
            bf8 b1 = *(const bf8*)&fw[r * 64 + 8 * SWZ(4 + fg, r)];

            u32 w[8][2];
            #pragma unroll
            for (int mh = 0; mh < 2; ++mh) {
                f32x4 hc[4];
                #pragma unroll
                for (int mm = 0; mm < 4; ++mm) {
                    const int m = mh * 4 + mm;
                    f32x4 z = {0.f, 0.f, 0.f, 0.f};
                    z = __builtin_amdgcn_mfma_f32_16x16x32_bf16(a1[m][0], b0, z, 0, 0, 0);
                    hc[mm] = __builtin_amdgcn_mfma_f32_16x16x32_bf16(a1[m][1], b1, z, 0, 0, 0);
                }
                #pragma unroll
                for (int mm = 0; mm < 4; ++mm) {
                    const int m = mh * 4 + mm;
                    w[m][0] = pk(fmaxf(hc[mm][0], 0.f), fmaxf(hc[mm][1], 0.f));
                    w[m][1] = pk(fmaxf(hc[mm][2], 0.f), fmaxf(hc[mm][3], 0.f));
                }
            }

            // layer 2: B-fragment from the lane's own words (register-only, r13)
            f32x4 uacc = {0.f, 0.f, 0.f, 0.f};
            #pragma unroll
            for (int kt = 0; kt < 4; ++kt) {
                union { u32 u[4]; bf8 v; } bb;
                bb.u[0] = w[2 * kt][0];
                bb.u[1] = w[2 * kt][1];
                bb.u[2] = w[2 * kt + 1][0];
                bb.u[3] = w[2 * kt + 1][1];
                uacc = __builtin_amdgcn_mfma_f32_16x16x32_bf16(a2[kt], bb.v, uacc, 0, 0, 0);
            }

            const int xo = px0 + g4 * 16 + fj;
            float* po = out + (((size_t)(b * STATE + 4 * fg)) * HH + y) * WW + xo;
            #pragma unroll
            for (int rr = 0; rr < 4; ++rr)
                po[(size_t)rr * HW] = uacc[rr];
        }
    }
}

extern "C" void kernel_launch(void* const* d_in, const int* in_sizes, int n_in,
                              void* d_out, int out_size, void* d_ws, size_t ws_size,
                              hipStream_t stream) {
    const float* x   = (const float*)d_in[0];
    const float* dna = (const float*)d_in[1];
    const float* w1  = (const float*)d_in[2];
    const float* w2  = (const float*)d_in[3];
    float* out = (float*)d_out;
    u16* wb = (u16*)d_ws;   // 10240 u16 = 20 KB

    prep_weights<<<dim3(40), dim3(256), 0, stream>>>(w1, w2, wb);

    const int B = in_sizes[0] / (STATE * HH * WW);   // 16
    const int nrows = B * HH;                        // 4096
    const int grid = (nrows < 768) ? nrows : 768;    // 3 blocks/CU persistent
    update_net18<<<dim3(grid), dim3(256), 0, stream>>>(x, dna, wb, out, nrows);
}

// Round 19
// 69.597 us; speedup vs baseline: 1.7482x; 1.1331x over previous
//
#include <hip/hip_runtime.h>
#include <hip/hip_bf16.h>

#define STATE 16
#define DNA_C 4
#define HID   128
#define FAN1  52
#define HH    256
#define WW    256
#define HW    (HH * WW)

typedef unsigned short u16;
typedef unsigned int   u32;
typedef short bf8 __attribute__((ext_vector_type(8)));
typedef float f32x4 __attribute__((ext_vector_type(4)));

__device__ __forceinline__ u32 pk(float a, float b) {
    __hip_bfloat162 t = __float22bfloat162_rn(make_float2(a, b));  // v_cvt_pk_bf16_f32
    union { __hip_bfloat162 h; u32 u; } c; c.h = t; return c.u;
}
__device__ __forceinline__ u16 f2bf(float f) {
    union { __hip_bfloat16 h; u16 u; } c; c.h = __float2bfloat16(f); return c.u;
}

// LDS-only barrier: cross-wave data inside the kernel flows ONLY through LDS, so we
// drain lgkmcnt but deliberately leave vmcnt (out-stores, next-row x-loads) in flight
// across the barrier — removes __syncthreads' vmcnt(0) store-ack stall every row (T4).
__device__ __forceinline__ void lds_barrier() {
    __builtin_amdgcn_sched_barrier(0);
    asm volatile("s_waitcnt lgkmcnt(0)" ::: "memory");
    __builtin_amdgcn_s_barrier();
    __builtin_amdgcn_sched_barrier(0);   // rule #18: no LDS op migrates across the barrier
}

// w1 [128][52] f32 -> bf16 [128][64], DOUBLY permuted (identical to round 13):
//  * k-permutation: knew = 16w + t (t0-3 x, t4-7 gx, t8-11 gy, t12-15 dna(w==0)/pad)
//  * M-permutation: physical row p=16m+4g+r holds true hidden H = 32(m>>1)+8g+4(m&1)+r
//    -> L1 D-fragment IS the L2 B-fragment (register-only layer-2 exchange).
// w2 [16][128] -> bf16 plain.
__global__ void prep_weights(const float* __restrict__ w1, const float* __restrict__ w2,
                             u16* __restrict__ wb) {
    int i = blockIdx.x * 256 + threadIdx.x;   // 0..10239
    if (i < 128 * 64) {
        int p = i >> 6, knew = i & 63;
        int m = p >> 4, g = (p >> 2) & 3, r = p & 3;
        int hrow = 32 * (m >> 1) + 8 * g + 4 * (m & 1) + r;   // true hidden row at physical p
        int w = knew >> 4, t = knew & 15;
        float v = 0.f;
        if (t < 4)        v = w1[hrow * FAN1 + 4 * w + t];
        else if (t < 8)   v = w1[hrow * FAN1 + 16 + 4 * w + (t - 4)];
        else if (t < 12)  v = w1[hrow * FAN1 + 32 + 4 * w + (t - 8)];
        else if (w == 0)  v = w1[hrow * FAN1 + 48 + (t - 12)];
        wb[i] = f2bf(v);
    } else if (i < 128 * 64 + 16 * 128) {
        wb[i] = f2bf(w2[i - 128 * 64]);
    }
}

__global__ __launch_bounds__(256, 3) void update_net19(
    const float* __restrict__ x,    // [B,16,256,256]
    const float* __restrict__ dna,  // [B,4,256,256]
    const u16*   __restrict__ wb,   // permuted bf16 w1 [128][64], w2 [16][128]
    float* __restrict__ out,        // [B,16,256,256]
    int nrows)                      // B*256
{
    // Round-16 champion structure, with __syncthreads replaced by lds_barrier():
    //  * 768 persistent blocks (3/CU), contiguous row chunks, weights loaded once.
    //  * feat: [256 px][64 k] bf16, chunks swizzled chunk ^= (px>>2)&7, 32 KB.
    //  * Two LDS-only barriers per row; global stores / loads stay in flight across them.
    __shared__ __align__(16) u16 feat_lds[256 * 64];

    const int tid  = threadIdx.x;
    const int lane = tid & 63;
    const int wv   = tid >> 6;
    const int fj   = lane & 15;   // A-row / B-col / D-col
    const int fg   = lane >> 4;   // k-group (A/B), row-group (D)
    const int f4   = fj >> 2;     // feat read swizzle base

    // ---- weight fragments ONCE per block (register-resident a1/a2, r13 layout) ----
    const u16* w1b = wb;             // [128][64] doubly permuted
    const u16* w2b = wb + 128 * 64;  // [16][128]
    bf8 a1[8][2];
    #pragma unroll
    for (int m = 0; m < 8; ++m) {
        #pragma unroll
        for (int kt = 0; kt < 2; ++kt)
            a1[m][kt] = *(const bf8*)&w1b[(16 * m + fj) * 64 + 32 * kt + 8 * fg];
    }
    bf8 a2[4];
    #pragma unroll
    for (int kt = 0; kt < 4; ++kt)
        a2[kt] = *(const bf8*)&w2b[fj * 128 + 32 * kt + 8 * fg];

    // ---- bijective contiguous chunking of rows over blocks ----
    const int ngrid = gridDim.x;
    const int q = nrows / ngrid, rm = nrows - q * ngrid;
    const int bid = blockIdx.x;
    const int start = (bid < rm) ? bid * (q + 1) : rm * (q + 1) + (bid - rm) * q;
    const int cnt   = (bid < rm) ? q + 1 : q;

    for (int it = 0; it < cnt; ++it) {
        const int yr = start + it;
        const int b  = yr >> 8;
        const int y  = yr & 255;
        const bool ht = (y > 0), hb = (y < HH - 1);   // block-uniform

        // ---- feature phase: wave wv -> channels 4wv..4wv+3, full row, 4 px/lane ----
        {
            const int px0 = lane * 4;
            const float* base = x + (((size_t)(b * STATE + 4 * wv)) * HH + y) * WW + px0;

            f32x4 xm[4], gx[4], gy[4];
            #pragma unroll
            for (int c = 0; c < 4; ++c) {
                const float* p = base + (size_t)c * HW;
                f32x4 m4 = *(const f32x4*)p;
                f32x4 t4 = {0.f,0.f,0.f,0.f}, b4 = {0.f,0.f,0.f,0.f};
                if (ht) t4 = *(const f32x4*)(p - WW);
                if (hb) b4 = *(const f32x4*)(p + WW);
                f32x4 cs, d;
                #pragma unroll
                for (int i = 0; i < 4; ++i) {
                    cs[i] = fmaf(2.f, m4[i], t4[i] + b4[i]);   // colsum t+2m+b
                    d[i]  = b4[i] - t4[i];
                }
                float csL = __shfl_up(cs[3], 1);
                float csR = __shfl_down(cs[0], 1);
                float dL  = __shfl_up(d[3], 1);
                float dR  = __shfl_down(d[0], 1);
                if (lane == 0)  { csL = 0.f; dL = 0.f; }       // image left border
                if (lane == 63) { csR = 0.f; dR = 0.f; }       // image right border
                xm[c] = m4;
                gx[c][0] = cs[1] - csL;   gx[c][1] = cs[2] - cs[0];
                gx[c][2] = cs[3] - cs[1]; gx[c][3] = csR - cs[2];
                gy[c][0] = fmaf(2.f, d[0], dL + d[1]);
                gy[c][1] = fmaf(2.f, d[1], d[0] + d[2]);
                gy[c][2] = fmaf(2.f, d[2], d[1] + d[3]);
                gy[c][3] = fmaf(2.f, d[3], d[2] + dR);
            }
            f32x4 dn[4] = {{0,0,0,0},{0,0,0,0},{0,0,0,0},{0,0,0,0}};
            if (wv == 0) {
                #pragma unroll
                for (int dc = 0; dc < 4; ++dc)
                    dn[dc] = *(const f32x4*)(dna + (((size_t)(b * DNA_C + dc)) * HH + y) * WW + px0);
            }
            const int s = lane & 7;   // (px>>2)&7 for all 4 px of this lane
            #pragma unroll
            for (int i = 0; i < 4; ++i) {
                u16* rowp = &feat_lds[(px0 + i) * 64];
                uint4 c0 = make_uint4(pk(xm[0][i], xm[1][i]), pk(xm[2][i], xm[3][i]),
                                      pk(gx[0][i], gx[1][i]), pk(gx[2][i], gx[3][i]));
                uint4 c1 = make_uint4(pk(gy[0][i], gy[1][i]), pk(gy[2][i], gy[3][i]),
                                      pk(dn[0][i], dn[1][i]), pk(dn[2][i], dn[3][i]));
                *(uint4*)&rowp[8 * ((2 * wv)     ^ s)] = c0;   // knew 16wv..+7  : x | gx
                *(uint4*)&rowp[8 * ((2 * wv + 1) ^ s)] = c1;   // knew 16wv+8..15: gy | dna/pad
            }
        }

        lds_barrier();   // feature writes visible; global ops stay in flight

        #pragma unroll
        for (int g4 = 0; g4 < 4; ++g4) {
            const int r  = wv * 64 + g4 * 16 + fj;
            const int sg = (4 * g4 + f4) & 7;
            bf8 b0 = *(const bf8*)&feat_lds[r * 64 + 8 * ((0 + fg) ^ sg)];
            bf8 b1 = *(const bf8*)&feat_lds[r * 64 + 8 * ((4 + fg) ^ sg)];

            // ---- layer 1 in two m-halves; relu+pack into lane-local words ----
            u32 w[8][2];
            #pragma unroll
            for (int mh = 0; mh < 2; ++mh) {
                f32x4 hc[4];
                #pragma unroll
                for (int mm = 0; mm < 4; ++mm) {
                    const int m = mh * 4 + mm;
                    f32x4 z = {0.f, 0.f, 0.f, 0.f};
                    z = __builtin_amdgcn_mfma_f32_16x16x32_bf16(a1[m][0], b0, z, 0, 0, 0);
                    hc[mm] = __builtin_amdgcn_mfma_f32_16x16x32_bf16(a1[m][1], b1, z, 0, 0, 0);
                }
                #pragma unroll
                for (int mm = 0; mm < 4; ++mm) {
                    const int m = mh * 4 + mm;
                    w[m][0] = pk(fmaxf(hc[mm][0], 0.f), fmaxf(hc[mm][1], 0.f));
                    w[m][1] = pk(fmaxf(hc[mm][2], 0.f), fmaxf(hc[mm][3], 0.f));
                }
            }

            // ---- layer 2: B-fragment from the lane's OWN words (register-only, r13) ----
            f32x4 uacc = {0.f, 0.f, 0.f, 0.f};
            #pragma unroll
            for (int kt = 0; kt < 4; ++kt) {
                union { u32 u[4]; bf8 v; } bb;
                bb.u[0] = w[2 * kt][0];
                bb.u[1] = w[2 * kt][1];
                bb.u[2] = w[2 * kt + 1][0];
                bb.u[3] = w[2 * kt + 1][1];
                uacc = __builtin_amdgcn_mfma_f32_16x16x32_bf16(a2[kt], bb.v, uacc, 0, 0, 0);
            }

            const int xo = wv * 64 + g4 * 16 + fj;
            float* po = out + (((size_t)(b * STATE + 4 * fg)) * HH + y) * WW + xo;
            #pragma unroll
            for (int rr2 = 0; rr2 < 4; ++rr2)
                po[(size_t)rr2 * HW] = uacc[rr2];
        }

        lds_barrier();   // MLP LDS reads done; stores continue in flight
    }
}

extern "C" void kernel_launch(void* const* d_in, const int* in_sizes, int n_in,
                              void* d_out, int out_size, void* d_ws, size_t ws_size,
                              hipStream_t stream) {
    const float* x   = (const float*)d_in[0];
    const float* dna = (const float*)d_in[1];
    const float* w1  = (const float*)d_in[2];
    const float* w2  = (const float*)d_in[3];
    float* out = (float*)d_out;
    u16* wb = (u16*)d_ws;   // 10240 u16 = 20 KB

    prep_weights<<<dim3(40), dim3(256), 0, stream>>>(w1, w2, wb);

    const int B = in_sizes[0] / (STATE * HH * WW);   // 16
    const int nrows = B * HH;                        // 4096
    const int grid = (nrows < 768) ? nrows : 768;    // 3 blocks/CU persistent
    update_net19<<<dim3(grid), dim3(256), 0, stream>>>(x, dna, wb, out, nrows);
}